// Round 7
// baseline (239.386 us; speedup 1.0000x reference)
//
#include <hip/hip_runtime.h>
#include <hip/hip_bf16.h>

// Problem constants: B=16, N=128, H_DIM=128, E_DIM=64, M_DIM=128
#define NB 16
#define NN 128
#define HD 128
#define ED 64
#define MD 128

typedef float f32x4 __attribute__((ext_vector_type(4)));

// ---------------------------------------------------------------------------
// Kernel 1 (verified): one block per row (b*N+n), 128 threads (= m).
//   hw1[row,m]  = h[row,:]@W1[:,m]
//   t2pb[row,m] = h[row,:]@W2[:,m] + bias[m]
// ---------------------------------------------------------------------------
__global__ __launch_bounds__(128, 8) void prep_kernel(
    const float* __restrict__ h, const float* __restrict__ W,
    const float* __restrict__ bias,
    float* __restrict__ hw1, float* __restrict__ t2pb)
{
    __shared__ float hs[HD];
    const int row = blockIdx.x;          // b*N + n
    const int m   = threadIdx.x;         // 0..127

    hs[m] = h[(size_t)row * HD + m];
    __syncthreads();

    float a1 = 0.f, a2 = 0.f;
    const float* W1p = W + m;                      // W rows 0..127
    const float* W2p = W + (size_t)HD * MD + m;    // W rows 128..255
#pragma unroll 8
    for (int d = 0; d < HD; ++d) {
        const float hv = hs[d];                    // uniform -> broadcast
        a1 = fmaf(hv, W1p[(size_t)d * MD], a1);
        a2 = fmaf(hv, W2p[(size_t)d * MD], a2);
    }
    hw1 [(size_t)row * MD + m] = a1;
    t2pb[(size_t)row * MD + m] = a2 + bias[m];
}

// ---------------------------------------------------------------------------
// Kernel 2: one block per (b,i), 256 threads = 4 waves (wave = m-quarter).
// Register tile R=2: lane owns j in {lane, lane+64}, 32 m's -> acc[2][32].
// One broadcast W3 quad feeds 8 FMAs (2 rows x 4 m) -> DS:FMA = 1:8.
// e rows loaded global->VGPR (L1/L2-hot, 4x wave reuse). LDS = 32 KB:
// W3[64][32 quads] linear during k-loop; tbuf[64][32 quads] (swizzled)
// overlays it in the two store half-phases.
// ---------------------------------------------------------------------------
__global__ __launch_bounds__(256, 4) void msg_kernel(
    const float* __restrict__ e, const float* __restrict__ adj,
    const float* __restrict__ W, const float* __restrict__ hw1,
    const float* __restrict__ t2pb, float* __restrict__ out)
{
    __shared__ float4 smem[2048];                 // 32768 B

    const int bx   = blockIdx.x;                  // b*N + i
    const int tid  = threadIdx.x;
    const int w    = __builtin_amdgcn_readfirstlane(tid >> 6);  // m-quarter 0..3
    const int lane = tid & 63;

    const float4* __restrict__ e4  = (const float4*)(e + (size_t)bx * NN * ED);
    const float4* __restrict__ W3q = (const float4*)(W + (size_t)(2 * HD) * MD);

    // ---- stage W3 linear [k=64][mq=32]: 2048 quads / 256 threads = 8 each
#pragma unroll
    for (int it = 0; it < 8; ++it)
        smem[tid + it * 256] = W3q[tid + it * 256];
    __syncthreads();

    const int wbase = 8 * w;        // quad offset of this wave's m-range in a k-row

    float acc[2][32];
#pragma unroll
    for (int r = 0; r < 2; ++r)
#pragma unroll
        for (int i = 0; i < 32; ++i) acc[r][i] = 0.f;

    // ---- k-loop: per q, 2 per-lane ev quads + 32 broadcast wv quads, 256 FMA
#pragma unroll 2
    for (int q = 0; q < 16; ++q) {
        const float4 ev0 = e4[lane * 16 + q];          // e row `lane`
        const float4 ev1 = e4[(lane + 64) * 16 + q];   // e row `lane+64`
#pragma unroll
        for (int kk = 0; kk < 4; ++kk) {
            const float e0 = (kk == 0) ? ev0.x : (kk == 1) ? ev0.y
                            : (kk == 2) ? ev0.z : ev0.w;
            const float e1 = (kk == 0) ? ev1.x : (kk == 1) ? ev1.y
                            : (kk == 2) ? ev1.z : ev1.w;
            const float4* __restrict__ wrow = smem + 32 * (4 * q + kk) + wbase;
#pragma unroll
            for (int p = 0; p < 8; ++p) {
                const float4 wv = wrow[p];             // broadcast ds_read_b128
                acc[0][4 * p + 0] = fmaf(e0, wv.x, acc[0][4 * p + 0]);
                acc[0][4 * p + 1] = fmaf(e0, wv.y, acc[0][4 * p + 1]);
                acc[0][4 * p + 2] = fmaf(e0, wv.z, acc[0][4 * p + 2]);
                acc[0][4 * p + 3] = fmaf(e0, wv.w, acc[0][4 * p + 3]);
                acc[1][4 * p + 0] = fmaf(e1, wv.x, acc[1][4 * p + 0]);
                acc[1][4 * p + 1] = fmaf(e1, wv.y, acc[1][4 * p + 1]);
                acc[1][4 * p + 2] = fmaf(e1, wv.z, acc[1][4 * p + 2]);
                acc[1][4 * p + 3] = fmaf(e1, wv.w, acc[1][4 * p + 3]);
            }
        }
    }

    // ---- store: two half-phases; tbuf overlays W3 (dead after k-loop)
    float4* __restrict__ tq = smem;               // 64 rows x 32 quads, swizzled
    const float*  __restrict__ adjrow = adj  + (size_t)bx * NN;
    const float4* __restrict__ hw1b   = (const float4*)(hw1 + (size_t)(bx >> 7) * NN * MD);
    const float4* __restrict__ t2row  = (const float4*)(t2pb + (size_t)bx * MD);
    f32x4*        __restrict__ outb   = (f32x4*)(out + (size_t)bx * NN * MD);

#pragma unroll
    for (int h = 0; h < 2; ++h) {
        __syncthreads();                // h=0: k-loop reads done; h=1: prev reads done
        {
            const int lx = lane & 7;
#pragma unroll
            for (int p = 0; p < 8; ++p) {
                const int qm = wbase + p;
                tq[32 * lane + (qm ^ lx)] =
                    make_float4(acc[h][4 * p + 0], acc[h][4 * p + 1],
                                acc[h][4 * p + 2], acc[h][4 * p + 3]);
            }
        }
        __syncthreads();
#pragma unroll
        for (int it = 0; it < 8; ++it) {
            const int t4 = tid + it * 256;        // 0..2047 quads of this j-half
            const int jl = t4 >> 5;               // 0..63 local row
            const int mq = t4 & 31;               // quad in row
            const int jg = h * 64 + jl;
            const float4 v  = tq[32 * jl + (mq ^ (jl & 7))];
            const float4 h1 = hw1b[(size_t)jg * 32 + mq];
            const float4 t2 = t2row[mq];
            const float  a  = adjrow[jg];
            f32x4 r;
            r.x = (v.x + h1.x + t2.x) * a;
            r.y = (v.y + h1.y + t2.y) * a;
            r.z = (v.z + h1.z + t2.z) * a;
            r.w = (v.w + h1.w + t2.w) * a;
            __builtin_nontemporal_store(r, outb + (size_t)jg * 32 + mq);
        }
    }
}

// ---------------------------------------------------------------------------
extern "C" void kernel_launch(void* const* d_in, const int* in_sizes, int n_in,
                              void* d_out, int out_size, void* d_ws, size_t ws_size,
                              hipStream_t stream)
{
    const float* h    = (const float*)d_in[0];
    const float* e    = (const float*)d_in[1];
    const float* adj  = (const float*)d_in[2];
    const float* W    = (const float*)d_in[3];
    const float* bias = (const float*)d_in[4];
    float* out = (float*)d_out;

    float* hw1  = (float*)d_ws;                       // (B*N, MD) = 1 MB
    float* t2pb = hw1 + (size_t)NB * NN * MD;         // (B*N, MD) = 1 MB

    prep_kernel<<<dim3(NB * NN), dim3(128), 0, stream>>>(h, W, bias, hw1, t2pb);
    msg_kernel <<<dim3(NB * NN), dim3(256), 0, stream>>>(e, adj, W, hw1, t2pb, out);
}

// Round 10
// 209.414 us; speedup vs baseline: 1.1431x; 1.1431x over previous
//
#include <hip/hip_runtime.h>
#include <hip/hip_bf16.h>

// Problem constants: B=16, N=128, H_DIM=128, E_DIM=64, M_DIM=128
#define NB 16
#define NN 128
#define HD 128
#define ED 64
#define MD 128

typedef float f32x4 __attribute__((ext_vector_type(4)));
typedef short bf16x8 __attribute__((ext_vector_type(8)));   // 8 bf16 (4 VGPRs)

// bit-split packing: hi = top 16 bits of fp32 (exact bf16), lo = bf16(x - hi)
__device__ __forceinline__ unsigned pack_hi(float a, float b) {
    return (__float_as_uint(a) >> 16) | (__float_as_uint(b) & 0xFFFF0000u);
}
__device__ __forceinline__ unsigned pack_lo(float a, float b) {
    const float ra = a - __uint_as_float(__float_as_uint(a) & 0xFFFF0000u);
    const float rb = b - __uint_as_float(__float_as_uint(b) & 0xFFFF0000u);
    return (__float_as_uint(ra) >> 16) | (__float_as_uint(rb) & 0xFFFF0000u);
}

// ---------------------------------------------------------------------------
// Kernel 1 (verified): one block per row (b*N+n), 128 threads (= m).
//   hw1[row,m]  = h[row,:]@W1[:,m]
//   t2pb[row,m] = h[row,:]@W2[:,m] + bias[m]
// ---------------------------------------------------------------------------
__global__ __launch_bounds__(128, 8) void prep_kernel(
    const float* __restrict__ h, const float* __restrict__ W,
    const float* __restrict__ bias,
    float* __restrict__ hw1, float* __restrict__ t2pb)
{
    __shared__ float hs[HD];
    const int row = blockIdx.x;          // b*N + n
    const int m   = threadIdx.x;         // 0..127

    hs[m] = h[(size_t)row * HD + m];
    __syncthreads();

    float a1 = 0.f, a2 = 0.f;
    const float* W1p = W + m;                      // W rows 0..127
    const float* W2p = W + (size_t)HD * MD + m;    // W rows 128..255
#pragma unroll 8
    for (int d = 0; d < HD; ++d) {
        const float hv = hs[d];                    // uniform -> broadcast
        a1 = fmaf(hv, W1p[(size_t)d * MD], a1);
        a2 = fmaf(hv, W2p[(size_t)d * MD], a2);
    }
    hw1 [(size_t)row * MD + m] = a1;
    t2pb[(size_t)row * MD + m] = a2 + bias[m];
}

// ---------------------------------------------------------------------------
// Kernel 2: one block per (b,i), 512 threads = 8 waves.
// Split-bf16 3-pass MFMA GEMM: C = eh.wh + eh.wl + el.wh  (~fp32 exact).
// LDS map (64 KB, all bf16 [row][k] k-contig, byte ^= (row&7)<<4 swizzle):
//   eh @ 0      el @ 16384     wh @ 32768     wl @ 49152
// After MFMA the whole 64 KB becomes tbuf[128][128] f32 (swizzled) for the
// coalesced fused epilogue: out = (C + hw1[b,j,:] + t2pb[b,i,:]) * adj[b,i,j].
// ---------------------------------------------------------------------------
__global__ __launch_bounds__(512, 4) void msg_kernel(
    const float* __restrict__ e, const float* __restrict__ adj,
    const float* __restrict__ W, const float* __restrict__ hw1,
    const float* __restrict__ t2pb, float* __restrict__ out)
{
    __shared__ char smem[65536];

    const int bx   = blockIdx.x;                  // b*N + i
    const int tid  = threadIdx.x;
    const int lane = tid & 63;
    const int w    = __builtin_amdgcn_readfirstlane(tid >> 6);  // wave 0..7

    // ================= staging (wave-split roles) =================
    if (w < 4) {
        // ---- W3 -> wh/wl : thread owns column m, k-half kh (32 k's)
        const int m  = tid & 127;
        const int kh = tid >> 7;                  // 0..1
        const float* __restrict__ W3 = W + (size_t)(2 * HD) * MD;
        float col[32];
#pragma unroll
        for (int k = 0; k < 32; ++k)
            col[k] = W3[(size_t)(kh * 32 + k) * MD + m];   // coalesced over m
        const unsigned swz = (unsigned)((m & 7) << 4);
#pragma unroll
        for (int q = 0; q < 4; ++q) {             // 8 k's -> 16B hi + 16B lo
            uint4 hi, lo;
            hi.x = pack_hi(col[8*q+0], col[8*q+1]);
            hi.y = pack_hi(col[8*q+2], col[8*q+3]);
            hi.z = pack_hi(col[8*q+4], col[8*q+5]);
            hi.w = pack_hi(col[8*q+6], col[8*q+7]);
            lo.x = pack_lo(col[8*q+0], col[8*q+1]);
            lo.y = pack_lo(col[8*q+2], col[8*q+3]);
            lo.z = pack_lo(col[8*q+4], col[8*q+5]);
            lo.w = pack_lo(col[8*q+6], col[8*q+7]);
            const unsigned off = (unsigned)((m << 7) + (kh << 6) + (q << 4)) ^ swz;
            *(uint4*)(smem + 32768 + off) = hi;
            *(uint4*)(smem + 49152 + off) = lo;
        }
    } else {
        // ---- e -> eh/el : 256 threads x 8 coalesced float4
        const int s = tid - 256;                  // 0..255
        const float4* __restrict__ e4 = (const float4*)(e + (size_t)bx * NN * ED);
        float4 ev[8];
#pragma unroll
        for (int it = 0; it < 8; ++it)
            ev[it] = e4[it * 256 + s];            // fully coalesced
#pragma unroll
        for (int it = 0; it < 8; ++it) {
            const int idx = it * 256 + s;         // quad index 0..2047
            const int j   = idx >> 4;             // e row
            const int kq  = idx & 15;             // k-quad (4 floats)
            const unsigned off =
                ((unsigned)((j << 7) + (kq << 3))) ^ (unsigned)((j & 7) << 4);
            uint2 hi, lo;
            hi.x = pack_hi(ev[it].x, ev[it].y);
            hi.y = pack_hi(ev[it].z, ev[it].w);
            lo.x = pack_lo(ev[it].x, ev[it].y);
            lo.y = pack_lo(ev[it].z, ev[it].w);
            *(uint2*)(smem + off)         = hi;
            *(uint2*)(smem + 16384 + off) = lo;
        }
    }
    __syncthreads();

    // ================= MFMA main: wave tile 64(j) x 32(m) =================
    const int jh  = w & 1;                        // j-half
    const int mq  = w >> 1;                       // m-quarter 0..3
    const int jb  = jh * 64;
    const int mb  = mq * 32;
    const int l15 = lane & 15;
    const int g   = lane >> 4;

    f32x4 acc[4][2];
#pragma unroll
    for (int jt = 0; jt < 4; ++jt)
#pragma unroll
        for (int mt = 0; mt < 2; ++mt)
            acc[jt][mt] = (f32x4){0.f, 0.f, 0.f, 0.f};

#pragma unroll
    for (int pass = 0; pass < 3; ++pass) {
        const int abase = (pass == 2) ? 16384 : 0;       // el : eh
        const int bbase = (pass == 1) ? 49152 : 32768;   // wl : wh
#pragma unroll
        for (int kt = 0; kt < 2; ++kt) {
            bf16x8 a[4], b[2];
#pragma unroll
            for (int jt = 0; jt < 4; ++jt) {
                const int j = jb + jt * 16 + l15;
                const unsigned off =
                    ((unsigned)((j << 7) + (kt << 6) + (g << 4)))
                    ^ (unsigned)((j & 7) << 4);
                a[jt] = *(const bf16x8*)(smem + abase + off);
            }
#pragma unroll
            for (int mt = 0; mt < 2; ++mt) {
                const int mm = mb + mt * 16 + l15;
                const unsigned off =
                    ((unsigned)((mm << 7) + (kt << 6) + (g << 4)))
                    ^ (unsigned)((mm & 7) << 4);
                b[mt] = *(const bf16x8*)(smem + bbase + off);
            }
#pragma unroll
            for (int jt = 0; jt < 4; ++jt)
#pragma unroll
                for (int mt = 0; mt < 2; ++mt)
                    acc[jt][mt] = __builtin_amdgcn_mfma_f32_16x16x32_bf16(
                        a[jt], b[mt], acc[jt][mt], 0, 0, 0);
        }
    }
    __syncthreads();            // all LDS reads done before tbuf overwrite

    // ================= acc -> swizzled tbuf (f32, 64 KB) =================
    // C/D layout: col = lane&15, row = (lane>>4)*4 + reg   [m89/m91]
#pragma unroll
    for (int jt = 0; jt < 4; ++jt) {
#pragma unroll
        for (int mt = 0; mt < 2; ++mt) {
#pragma unroll
            for (int r = 0; r < 4; ++r) {
                const int j  = jb + jt * 16 + g * 4 + r;
                const int mm = mb + mt * 16 + l15;
                const unsigned off =
                    ((unsigned)((j << 9) + (mm << 2)))
                    ^ (unsigned)((j & 7) << 4);
                *(float*)(smem + off) = acc[jt][mt][r];
            }
        }
    }
    __syncthreads();

    // ================= fused coalesced epilogue =================
    const float*  __restrict__ adjrow = adj  + (size_t)bx * NN;
    const float4* __restrict__ hw1b   = (const float4*)(hw1 + (size_t)(bx >> 7) * NN * MD);
    const float4* __restrict__ t2row  = (const float4*)(t2pb + (size_t)bx * MD);
    f32x4*        __restrict__ outb   = (f32x4*)(out + (size_t)bx * NN * MD);

#pragma unroll
    for (int it = 0; it < 8; ++it) {
        const int t4 = tid + it * 512;            // 0..4095 quads
        const int j  = t4 >> 5;                   // row 0..127
        const int q  = t4 & 31;                   // m-quad 0..31
        const unsigned off =
            ((unsigned)((j << 9) + (q << 4))) ^ (unsigned)((j & 7) << 4);
        const float4 v  = *(const float4*)(smem + off);
        const float4 h1 = hw1b[(size_t)j * 32 + q];
        const float4 t2 = t2row[q];
        const float  a  = adjrow[j];
        f32x4 r;
        r.x = (v.x + h1.x + t2.x) * a;
        r.y = (v.y + h1.y + t2.y) * a;
        r.z = (v.z + h1.z + t2.z) * a;
        r.w = (v.w + h1.w + t2.w) * a;
        __builtin_nontemporal_store(r, outb + (size_t)j * 32 + q);
    }
}

// ---------------------------------------------------------------------------
extern "C" void kernel_launch(void* const* d_in, const int* in_sizes, int n_in,
                              void* d_out, int out_size, void* d_ws, size_t ws_size,
                              hipStream_t stream)
{
    const float* h    = (const float*)d_in[0];
    const float* e    = (const float*)d_in[1];
    const float* adj  = (const float*)d_in[2];
    const float* W    = (const float*)d_in[3];
    const float* bias = (const float*)d_in[4];
    float* out = (float*)d_out;

    float* hw1  = (float*)d_ws;                       // (B*N, MD) = 1 MB
    float* t2pb = hw1 + (size_t)NB * NN * MD;         // (B*N, MD) = 1 MB

    prep_kernel<<<dim3(NB * NN), dim3(128), 0, stream>>>(h, W, bias, hw1, t2pb);
    msg_kernel <<<dim3(NB * NN), dim3(512), 0, stream>>>(e, adj, W, hw1, t2pb, out);
}